// Round 1
// baseline (13464.690 us; speedup 1.0000x reference)
//
#include <hip/hip_runtime.h>
#include <cstddef>

// Problem constants
constexpr int B = 128;
constexpr int T = 500;
constexpr int C = 128;     // n_maps
constexpr int CIN = 80;    // n_mels
constexpr int NL = 35;     // labels
constexpr size_t NBCT = (size_t)B * C * T;  // 8,192,000 floats = 32.768 MB

// Static device scratch (avoids ws_size assumptions).
__device__ float g_z[NBCT];
__device__ float g_acc[NBCT];
__device__ float g_zin[NBCT];
__device__ float g_t1[NBCT];
__device__ float g_t2[NBCT];
__device__ float g_t3[NBCT];
__device__ float g_ps1[1024], g_pq1[1024];
__device__ float g_ps2[1024], g_pq2[1024];
__device__ float g_ps3[1024], g_pq3[1024];

// ---------------------------------------------------------------------------
// Tiled implicit-GEMM conv over the T axis.
// in: [B][I][T], w: [C][I][KW] (contig), out: [B][C][T]
// Block computes a 128(outch) x 128(t) tile for one b. 256 threads, 8x8/thread.
// ---------------------------------------------------------------------------
template <int I, int KW, int PAD>
__global__ __launch_bounds__(256) void conv_kernel(
    const float* __restrict__ in, const float* __restrict__ w,
    float* __restrict__ out) {
  constexpr int KTOT = I * KW;             // 240 / 1152 / 128 — all %16==0
  constexpr int NCHUNK = KTOT / 16;
  __shared__ __align__(16) float As[16][132];
  __shared__ __align__(16) float Bs[16][132];

  const int tile = blockIdx.x;   // t0 = tile*128
  const int b = blockIdx.y;
  const int t0 = tile * 128;
  const int tid = threadIdx.x;
  const int tx = tid & 15;       // col group
  const int ty = tid >> 4;       // row group

  const float* __restrict__ inb = in + (size_t)b * I * T;

  float acc[8][8];
#pragma unroll
  for (int i = 0; i < 8; i++)
#pragma unroll
    for (int j = 0; j < 8; j++) acc[i][j] = 0.f;

  for (int kc = 0; kc < NCHUNK; kc++) {
    const int kbase = kc * 16;
    // Stage A (weights): As[kk][o] = w[o*KTOT + kbase + kk]
#pragma unroll
    for (int r = 0; r < 8; r++) {
      int e = r * 256 + tid;          // [0,2048)
      int kkin = e & 15;
      int o = e >> 4;
      As[kkin][o] = w[(size_t)o * KTOT + kbase + kkin];
    }
    // Stage B (input patches): Bs[kk][col] = in[b][i][t0+col+kw-PAD]
#pragma unroll
    for (int r = 0; r < 8; r++) {
      int e = r * 256 + tid;          // [0,2048)
      int col = e & 127;
      int kkin = e >> 7;
      int kk = kbase + kkin;
      int ii = kk / KW;
      int kw = kk % KW;
      int t = t0 + col + kw - PAD;
      float v = 0.f;
      if (t >= 0 && t < T) v = inb[(size_t)ii * T + t];
      Bs[kkin][col] = v;
    }
    __syncthreads();
#pragma unroll
    for (int kk = 0; kk < 16; kk++) {
      float4 a0 = *(const float4*)&As[kk][ty * 8];
      float4 a1 = *(const float4*)&As[kk][ty * 8 + 4];
      float4 b0 = *(const float4*)&Bs[kk][tx * 8];
      float4 b1 = *(const float4*)&Bs[kk][tx * 8 + 4];
      float av[8] = {a0.x, a0.y, a0.z, a0.w, a1.x, a1.y, a1.z, a1.w};
      float bv[8] = {b0.x, b0.y, b0.z, b0.w, b1.x, b1.y, b1.z, b1.w};
#pragma unroll
      for (int i = 0; i < 8; i++)
#pragma unroll
        for (int j = 0; j < 8; j++)
          acc[i][j] = fmaf(av[i], bv[j], acc[i][j]);
    }
    __syncthreads();
  }

  float* __restrict__ outb = out + (size_t)b * C * T;
#pragma unroll
  for (int i = 0; i < 8; i++) {
    int o = ty * 8 + i;
#pragma unroll
    for (int j = 0; j < 8; j++) {
      int t = t0 + tx * 8 + j;
      if (t < T) outb[(size_t)o * T + t] = acc[i][j];
    }
  }
}

// ---------------------------------------------------------------------------
// BN partial stats: grid (8, C). Block (sb, c) sums 16 b's x 500 t.
// ---------------------------------------------------------------------------
__inline__ __device__ float wave_sum(float v) {
  for (int off = 32; off; off >>= 1) v += __shfl_down(v, off);
  return v;
}

__global__ __launch_bounds__(256) void bn_stats_kernel(
    const float* __restrict__ x, float* __restrict__ psum,
    float* __restrict__ psq) {
  const int sb = blockIdx.x;   // 0..7
  const int c = blockIdx.y;    // 0..127
  const int b0 = sb * 16;
  const int tid = threadIdx.x;
  const int NE = 16 * T;  // 8000
  float s = 0.f, ss = 0.f;
  for (int e = tid; e < NE; e += 256) {
    int b = b0 + e / T;
    int t = e % T;
    float v = x[((size_t)b * C + c) * T + t];
    s += v;
    ss += v * v;
  }
  __shared__ float ls[8];
  float sw = wave_sum(s);
  float qw = wave_sum(ss);
  int wave = tid >> 6, lane = tid & 63;
  if (lane == 0) { ls[wave] = sw; ls[4 + wave] = qw; }
  __syncthreads();
  if (tid == 0) {
    psum[c * 8 + sb] = ls[0] + ls[1] + ls[2] + ls[3];
    psq[c * 8 + sb] = ls[4] + ls[5] + ls[6] + ls[7];
  }
}

__inline__ __device__ void finalize_stats(const float* __restrict__ ps,
                                          const float* __restrict__ pq, int c,
                                          float& m, float& r) {
  float s = 0.f, q = 0.f;
  for (int i = 0; i < 8; i++) { s += ps[c * 8 + i]; q += pq[c * 8 + i]; }
  m = s * (1.f / 64000.f);
  float v = q * (1.f / 64000.f) - m * m;
  r = rsqrtf(v + 1e-5f);
}

// ---------------------------------------------------------------------------
// In-place x = relu((x - mean) * rstd). grid (C, 16): 8 b's per block.
// ---------------------------------------------------------------------------
__global__ __launch_bounds__(256) void bn_apply_relu_kernel(
    float* __restrict__ x, const float* __restrict__ ps,
    const float* __restrict__ pq) {
  const int c = blockIdx.x;
  const int bg = blockIdx.y;
  __shared__ float sm, sr;
  if (threadIdx.x == 0) {
    float m, r;
    finalize_stats(ps, pq, c, m, r);
    sm = m; sr = r;
  }
  __syncthreads();
  const float m = sm, r = sr;
  const int b0 = bg * 8;
  for (int e = threadIdx.x; e < 1000; e += 256) {  // 8 rows x 125 float4
    int b = b0 + e / 125;
    int q4 = e % 125;
    float4* p = (float4*)(x + ((size_t)b * C + c) * T) + q4;
    float4 v = *p;
    v.x = fmaxf((v.x - m) * r, 0.f);
    v.y = fmaxf((v.y - m) * r, 0.f);
    v.z = fmaxf((v.z - m) * r, 0.f);
    v.w = fmaxf((v.w - m) * r, 0.f);
    *p = v;
  }
}

// ---------------------------------------------------------------------------
// combine: k = relu(bn2(t2) + relu(bn3(t3)));
//   acc = init ? wacc*k : acc + wacc*k
//   zout = fin ? z + anext*acc_new : z + anext*k
// grid (C, 16)
// ---------------------------------------------------------------------------
__global__ __launch_bounds__(256) void combine_kernel(
    const float* __restrict__ t2, const float* __restrict__ t3,
    const float* __restrict__ ps2, const float* __restrict__ pq2,
    const float* __restrict__ ps3, const float* __restrict__ pq3,
    const float* __restrict__ z, float* __restrict__ acc,
    float* __restrict__ zout, float wacc, float anext, int init, int fin) {
  const int c = blockIdx.x;
  const int bg = blockIdx.y;
  __shared__ float sm2, sr2, sm3, sr3;
  if (threadIdx.x == 0) {
    float m, r;
    finalize_stats(ps2, pq2, c, m, r); sm2 = m; sr2 = r;
    finalize_stats(ps3, pq3, c, m, r); sm3 = m; sr3 = r;
  }
  __syncthreads();
  const float m2 = sm2, r2 = sr2, m3 = sm3, r3 = sr3;
  const int b0 = bg * 8;
  for (int e = threadIdx.x; e < 1000; e += 256) {
    int b = b0 + e / 125;
    int q4 = e % 125;
    size_t off = ((size_t)b * C + c) * T + (size_t)q4 * 4;
    float4 v2 = *(const float4*)(t2 + off);
    float4 v3 = *(const float4*)(t3 + off);
    float4 vz = *(const float4*)(z + off);
    float4 k;
    k.x = fmaxf((v2.x - m2) * r2 + fmaxf((v3.x - m3) * r3, 0.f), 0.f);
    k.y = fmaxf((v2.y - m2) * r2 + fmaxf((v3.y - m3) * r3, 0.f), 0.f);
    k.z = fmaxf((v2.z - m2) * r2 + fmaxf((v3.z - m3) * r3, 0.f), 0.f);
    k.w = fmaxf((v2.w - m2) * r2 + fmaxf((v3.w - m3) * r3, 0.f), 0.f);
    float4 va;
    if (init) {
      va.x = wacc * k.x; va.y = wacc * k.y; va.z = wacc * k.z; va.w = wacc * k.w;
    } else {
      va = *(const float4*)(acc + off);
      va.x += wacc * k.x; va.y += wacc * k.y; va.z += wacc * k.z; va.w += wacc * k.w;
    }
    *(float4*)(acc + off) = va;
    float4 vo;
    if (fin) {
      vo.x = vz.x + anext * va.x; vo.y = vz.y + anext * va.y;
      vo.z = vz.z + anext * va.z; vo.w = vz.w + anext * va.w;
    } else {
      vo.x = vz.x + anext * k.x; vo.y = vz.y + anext * k.y;
      vo.z = vz.z + anext * k.z; vo.w = vz.w + anext * k.w;
    }
    *(float4*)(zout + off) = vo;
  }
}

// ---------------------------------------------------------------------------
// head: feat[b][c] = mean_t z, out[b][l] = feat . w[l] + bias[l]
// ---------------------------------------------------------------------------
__global__ __launch_bounds__(256) void head_kernel(
    const float* __restrict__ z, const float* __restrict__ ow,
    const float* __restrict__ ob, float* __restrict__ out) {
  const int b = blockIdx.x;
  const int wave = threadIdx.x >> 6;
  const int lane = threadIdx.x & 63;
  __shared__ float feat[C];
  for (int c = wave; c < C; c += 4) {
    const float* row = z + ((size_t)b * C + c) * T;
    float s = 0.f;
    for (int t = lane; t < T; t += 64) s += row[t];
    s = wave_sum(s);
    if (lane == 0) feat[c] = s * (1.f / 500.f);
  }
  __syncthreads();
  if (threadIdx.x < NL) {
    int l = threadIdx.x;
    float o = ob[l];
    for (int j = 0; j < C; j++) o = fmaf(feat[j], ow[l * C + j], o);
    out[b * NL + l] = o;
  }
}

// ---------------------------------------------------------------------------
extern "C" void kernel_launch(void* const* d_in, const int* in_sizes, int n_in,
                              void* d_out, int out_size, void* d_ws,
                              size_t ws_size, hipStream_t stream) {
  const float* x  = (const float*)d_in[0];
  const float* w0 = (const float*)d_in[1];
  const float* w1 = (const float*)d_in[2];
  const float* w2 = (const float*)d_in[3];
  const float* w3 = (const float*)d_in[4];
  const float* ow = (const float*)d_in[5];
  const float* ob = (const float*)d_in[6];
  float* out = (float*)d_out;

  static float *z = nullptr, *acc = nullptr, *zin = nullptr, *t1 = nullptr,
               *t2 = nullptr, *t3 = nullptr, *ps1 = nullptr, *pq1 = nullptr,
               *ps2 = nullptr, *pq2 = nullptr, *ps3 = nullptr, *pq3 = nullptr;
  static bool inited = false;
  if (!inited) {
    void* p;
    hipGetSymbolAddress(&p, HIP_SYMBOL(g_z));   z   = (float*)p;
    hipGetSymbolAddress(&p, HIP_SYMBOL(g_acc)); acc = (float*)p;
    hipGetSymbolAddress(&p, HIP_SYMBOL(g_zin)); zin = (float*)p;
    hipGetSymbolAddress(&p, HIP_SYMBOL(g_t1));  t1  = (float*)p;
    hipGetSymbolAddress(&p, HIP_SYMBOL(g_t2));  t2  = (float*)p;
    hipGetSymbolAddress(&p, HIP_SYMBOL(g_t3));  t3  = (float*)p;
    hipGetSymbolAddress(&p, HIP_SYMBOL(g_ps1)); ps1 = (float*)p;
    hipGetSymbolAddress(&p, HIP_SYMBOL(g_pq1)); pq1 = (float*)p;
    hipGetSymbolAddress(&p, HIP_SYMBOL(g_ps2)); ps2 = (float*)p;
    hipGetSymbolAddress(&p, HIP_SYMBOL(g_pq2)); pq2 = (float*)p;
    hipGetSymbolAddress(&p, HIP_SYMBOL(g_ps3)); ps3 = (float*)p;
    hipGetSymbolAddress(&p, HIP_SYMBOL(g_pq3)); pq3 = (float*)p;
    inited = true;
  }

  const dim3 convGrid(4, B);      // 4 t-tiles x 128 batch
  const dim3 statsGrid(8, C);     // 8 b-chunks x 128 channels
  const dim3 ewGrid(C, 16);       // channel x 8-b groups
  const float dt = 0.25f;         // INTEGRATION_TIME / NSTEPS

  // conv0 -> bn -> relu  (into z)
  conv_kernel<CIN, 3, 1><<<convGrid, 256, 0, stream>>>(x, w0, z);
  bn_stats_kernel<<<statsGrid, 256, 0, stream>>>(z, ps1, pq1);
  bn_apply_relu_kernel<<<ewGrid, 256, 0, stream>>>(z, ps1, pq1);

  const float waccs[4] = {1.f, 2.f, 2.f, 1.f};
  const float anexts[4] = {0.5f * dt, 0.5f * dt, dt, dt / 6.f};

  for (int step = 0; step < 4; step++) {
    for (int s = 0; s < 4; s++) {
      const float* zin_s = (s == 0) ? z : zin;
      // out-branch: conv1 -> bn+relu -> conv2 -> (bn in combine)
      conv_kernel<C, 9, 4><<<convGrid, 256, 0, stream>>>(zin_s, w1, t1);
      bn_stats_kernel<<<statsGrid, 256, 0, stream>>>(t1, ps1, pq1);
      bn_apply_relu_kernel<<<ewGrid, 256, 0, stream>>>(t1, ps1, pq1);
      conv_kernel<C, 9, 4><<<convGrid, 256, 0, stream>>>(t1, w2, t2);
      bn_stats_kernel<<<statsGrid, 256, 0, stream>>>(t2, ps2, pq2);
      // shortcut branch: conv3 -> (bn+relu in combine)
      conv_kernel<C, 1, 0><<<convGrid, 256, 0, stream>>>(zin_s, w3, t3);
      bn_stats_kernel<<<statsGrid, 256, 0, stream>>>(t3, ps3, pq3);
      // k = relu(bn(t2) + relu(bn(t3))); RK4 update fused
      combine_kernel<<<ewGrid, 256, 0, stream>>>(
          t2, t3, ps2, pq2, ps3, pq3, z, acc, (s == 3) ? z : zin,
          waccs[s], anexts[s], (s == 0) ? 1 : 0, (s == 3) ? 1 : 0);
    }
  }

  head_kernel<<<B, 256, 0, stream>>>(z, ow, ob, out);
}

// Round 2
// 3200.027 us; speedup vs baseline: 4.2077x; 4.2077x over previous
//
#include <hip/hip_runtime.h>
#include <hip/hip_bf16.h>
#include <cstddef>

// Problem constants
constexpr int B = 128;
constexpr int T = 500;
constexpr int C = 128;     // n_maps
constexpr int CIN = 80;    // n_mels
constexpr int NL = 35;     // labels
constexpr size_t NBCT = (size_t)B * C * T;  // 8,192,000 floats
constexpr int NPART = 1024;                 // partial-stats stride
constexpr int NT = 64;                      // t-tile for MFMA convs
constexpr int WPAD = 136;                   // padded i-stride for weights/LDS

typedef __attribute__((ext_vector_type(8))) short short8;   // 8 bf16 = 4 VGPR
typedef __attribute__((ext_vector_type(4))) float f32x4;

// Static device scratch. All tensors in [b][t][c] layout (c fastest).
__device__ float g_z[NBCT];
__device__ float g_acc[NBCT];
__device__ float g_zin[NBCT];
__device__ float g_t1[NBCT];
__device__ float g_t2[NBCT];
__device__ float g_t3[NBCT];
__device__ float g_ps1[C * NPART], g_pq1[C * NPART];
__device__ float g_ps2[C * NPART], g_pq2[C * NPART];
__device__ float g_ps3[C * NPART], g_pq3[C * NPART];
__device__ float g_m1[C], g_r1[C], g_m2[C], g_r2[C], g_m3[C], g_r3[C];
// Split bf16 weights, layout [kw][o][i] with i-stride WPAD
__device__ unsigned short g_w1h[9 * C * WPAD], g_w1l[9 * C * WPAD];
__device__ unsigned short g_w2h[9 * C * WPAD], g_w2l[9 * C * WPAD];
__device__ unsigned short g_w3h[1 * C * WPAD], g_w3l[1 * C * WPAD];

__device__ inline unsigned short f2bf(float x) {
  __hip_bfloat16 h = __float2bfloat16(x);
  return *(unsigned short*)&h;
}
__device__ inline float bf2f(unsigned short u) {
  __hip_bfloat16 h = *(__hip_bfloat16*)&u;
  return __bfloat162float(h);
}
__device__ inline void split_bf16(float x, unsigned short& h, unsigned short& l) {
  unsigned short hh = f2bf(x);
  h = hh;
  l = f2bf(x - bf2f(hh));
}

__inline__ __device__ float wave_sum(float v) {
  for (int off = 32; off; off >>= 1) v += __shfl_down(v, off);
  return v;
}

// ---------------------------------------------------------------------------
// Weight prep: w [O=128][I=128][KW] fp32 -> hi/lo bf16 [KW][O][WPAD]
// ---------------------------------------------------------------------------
template <int KW>
__global__ __launch_bounds__(256) void prep_weights(
    const float* __restrict__ w, unsigned short* __restrict__ wh,
    unsigned short* __restrict__ wl) {
  int idx = blockIdx.x * 256 + threadIdx.x;
  if (idx >= C * C * KW) return;
  int kw = idx % KW;
  int i = (idx / KW) % C;
  int o = idx / (KW * C);
  float x = w[idx];
  unsigned short h, l;
  split_bf16(x, h, l);
  size_t dst = ((size_t)kw * C + o) * WPAD + i;
  wh[dst] = h;
  wl[dst] = l;
}

// ---------------------------------------------------------------------------
// MFMA bf16x3 implicit-GEMM conv over T.
// in: [B][T][C] fp32 (optionally bn+relu applied during staging)
// weights: [KW][128 o][WPAD i] bf16 hi/lo
// out: [B][T][C] fp32, plus per-block channel partial sums ps/pq [c][NPART].
// Block: b = blockIdx.y, t-tile of 64 = blockIdx.x (grid 8 x 128).
// 4 waves; wave w computes o-groups {2w, 2w+1} x all 4 t-groups of 16.
// ---------------------------------------------------------------------------
template <int KW, int PAD, bool BNRELU>
__global__ __launch_bounds__(256) void conv_mfma(
    const float* __restrict__ in, const unsigned short* __restrict__ wh,
    const unsigned short* __restrict__ wl, const float* __restrict__ bnm,
    const float* __restrict__ bnr, float* __restrict__ out,
    float* __restrict__ ps, float* __restrict__ pq) {
  constexpr int ROWS = NT + KW - 1;
  __shared__ unsigned short shi[ROWS * WPAD];
  __shared__ unsigned short slo[ROWS * WPAD];
  __shared__ float ssum[C], ssq[C];
  __shared__ float sbm[C], sbr[C];

  const int tid = threadIdx.x;
  const int tile = blockIdx.x;
  const int b = blockIdx.y;
  const int t0 = tile * NT;

  if (BNRELU) {
    if (tid < 128) { sbm[tid] = bnm[tid]; sbr[tid] = bnr[tid]; }
  }
  if (tid < 128) { ssum[tid] = 0.f; ssq[tid] = 0.f; }
  __syncthreads();

  // Stage input rows [t0-PAD, t0-PAD+ROWS) as bf16 hi/lo into LDS.
  const float* __restrict__ inb = in + (size_t)b * T * C;
  constexpr int NF4 = ROWS * (C / 4);
  for (int e = tid; e < NF4; e += 256) {
    int r = e >> 5;       // row
    int c4 = e & 31;      // float4 within row
    int t = t0 - PAD + r;
    float4 v = make_float4(0.f, 0.f, 0.f, 0.f);
    if (t >= 0 && t < T) v = ((const float4*)(inb + (size_t)t * C))[c4];
    if (BNRELU) {
      int c = c4 * 4;
      v.x = fmaxf((v.x - sbm[c]) * sbr[c], 0.f);
      v.y = fmaxf((v.y - sbm[c + 1]) * sbr[c + 1], 0.f);
      v.z = fmaxf((v.z - sbm[c + 2]) * sbr[c + 2], 0.f);
      v.w = fmaxf((v.w - sbm[c + 3]) * sbr[c + 3], 0.f);
    }
    ushort4 hv, lv;
    split_bf16(v.x, hv.x, lv.x);
    split_bf16(v.y, hv.y, lv.y);
    split_bf16(v.z, hv.z, lv.z);
    split_bf16(v.w, hv.w, lv.w);
    int off = r * WPAD + c4 * 4;
    *(ushort4*)&shi[off] = hv;
    *(ushort4*)&slo[off] = lv;
  }
  __syncthreads();

  const int wv = tid >> 6;
  const int lane = tid & 63;
  const int quad = lane >> 4;
  const int m15 = lane & 15;
  const int og0 = wv * 2;

  f32x4 dacc[2][4];
#pragma unroll
  for (int g = 0; g < 2; g++)
#pragma unroll
    for (int tg = 0; tg < 4; tg++) dacc[g][tg] = f32x4{0.f, 0.f, 0.f, 0.f};

  for (int kw = 0; kw < KW; kw++) {
    const unsigned short* __restrict__ wkh = wh + (size_t)kw * C * WPAD;
    const unsigned short* __restrict__ wkl = wl + (size_t)kw * C * WPAD;
#pragma unroll
    for (int ic = 0; ic < 4; ic++) {
      const int kof = ic * 32 + quad * 8;
      short8 ah[2], al[2];
#pragma unroll
      for (int g = 0; g < 2; g++) {
        size_t off = (size_t)((og0 + g) * 16 + m15) * WPAD + kof;
        ah[g] = *(const short8*)(wkh + off);
        al[g] = *(const short8*)(wkl + off);
      }
      short8 bhf[4], blf[4];
#pragma unroll
      for (int tg = 0; tg < 4; tg++) {
        int r = tg * 16 + m15 + kw;
        int off = r * WPAD + kof;
        bhf[tg] = *(const short8*)(shi + off);
        blf[tg] = *(const short8*)(slo + off);
      }
#pragma unroll
      for (int g = 0; g < 2; g++)
#pragma unroll
        for (int tg = 0; tg < 4; tg++) {
          f32x4 d = dacc[g][tg];
          d = __builtin_amdgcn_mfma_f32_16x16x32_bf16(ah[g], bhf[tg], d, 0, 0, 0);
          d = __builtin_amdgcn_mfma_f32_16x16x32_bf16(ah[g], blf[tg], d, 0, 0, 0);
          d = __builtin_amdgcn_mfma_f32_16x16x32_bf16(al[g], bhf[tg], d, 0, 0, 0);
          dacc[g][tg] = d;
        }
    }
  }

  // Epilogue: store (D layout: col(t)=lane&15, row(o)=quad*4+reg) + partials.
  float* __restrict__ outb = out + (size_t)b * T * C;
#pragma unroll
  for (int g = 0; g < 2; g++) {
    float rs[4] = {0.f, 0.f, 0.f, 0.f}, rq[4] = {0.f, 0.f, 0.f, 0.f};
#pragma unroll
    for (int tg = 0; tg < 4; tg++) {
      int t = t0 + tg * 16 + m15;
      bool valid = t < T;
      f32x4 d = dacc[g][tg];
      if (valid)
        *(f32x4*)(outb + (size_t)t * C + (og0 + g) * 16 + quad * 4) = d;
#pragma unroll
      for (int r = 0; r < 4; r++) {
        float v = valid ? d[r] : 0.f;
        rs[r] += v;
        rq[r] += v * v;
      }
    }
#pragma unroll
    for (int sh = 1; sh < 16; sh <<= 1) {
#pragma unroll
      for (int r = 0; r < 4; r++) {
        rs[r] += __shfl_xor(rs[r], sh);
        rq[r] += __shfl_xor(rq[r], sh);
      }
    }
    if (m15 == 0) {
      int o = (og0 + g) * 16 + quad * 4;
#pragma unroll
      for (int r = 0; r < 4; r++) {
        atomicAdd(&ssum[o + r], rs[r]);
        atomicAdd(&ssq[o + r], rq[r]);
      }
    }
  }
  __syncthreads();
  int p = b * 8 + tile;
  if (tid < 128) {
    ps[tid * NPART + p] = ssum[tid];
    pq[tid * NPART + p] = ssq[tid];
  }
}

// ---------------------------------------------------------------------------
// conv0: fp32 VALU conv, in x[B][CIN][T], out [B][T][C] + partials.
// ---------------------------------------------------------------------------
__global__ __launch_bounds__(256) void conv0_kernel(
    const float* __restrict__ in, const float* __restrict__ w,
    float* __restrict__ out, float* __restrict__ ps, float* __restrict__ pq) {
  constexpr int KTOT = CIN * 3;  // 240
  constexpr int NCHUNK = KTOT / 16;
  __shared__ __align__(16) float As[16][132];
  __shared__ __align__(16) float Bs[16][132];
  __shared__ float ssum[C], ssq[C];

  const int tile = blockIdx.x;  // 4 tiles of 128 t
  const int b = blockIdx.y;
  const int t0 = tile * 128;
  const int tid = threadIdx.x;
  const int tx = tid & 15;
  const int ty = tid >> 4;
  if (tid < 128) { ssum[tid] = 0.f; ssq[tid] = 0.f; }

  const float* __restrict__ inb = in + (size_t)b * CIN * T;
  float acc[8][8];
#pragma unroll
  for (int i = 0; i < 8; i++)
#pragma unroll
    for (int j = 0; j < 8; j++) acc[i][j] = 0.f;

  for (int kc = 0; kc < NCHUNK; kc++) {
    const int kbase = kc * 16;
#pragma unroll
    for (int r = 0; r < 8; r++) {
      int e = r * 256 + tid;
      As[e & 15][e >> 4] = w[(size_t)(e >> 4) * KTOT + kbase + (e & 15)];
    }
#pragma unroll
    for (int r = 0; r < 8; r++) {
      int e = r * 256 + tid;
      int col = e & 127;
      int kkin = e >> 7;
      int kk = kbase + kkin;
      int ii = kk / 3;
      int kw = kk % 3;
      int t = t0 + col + kw - 1;
      float v = 0.f;
      if (t >= 0 && t < T) v = inb[(size_t)ii * T + t];
      Bs[kkin][col] = v;
    }
    __syncthreads();
#pragma unroll
    for (int kk = 0; kk < 16; kk++) {
      float4 a0 = *(const float4*)&As[kk][ty * 8];
      float4 a1 = *(const float4*)&As[kk][ty * 8 + 4];
      float4 b0 = *(const float4*)&Bs[kk][tx * 8];
      float4 b1 = *(const float4*)&Bs[kk][tx * 8 + 4];
      float av[8] = {a0.x, a0.y, a0.z, a0.w, a1.x, a1.y, a1.z, a1.w};
      float bv[8] = {b0.x, b0.y, b0.z, b0.w, b1.x, b1.y, b1.z, b1.w};
#pragma unroll
      for (int i = 0; i < 8; i++)
#pragma unroll
        for (int j = 0; j < 8; j++)
          acc[i][j] = fmaf(av[i], bv[j], acc[i][j]);
    }
    __syncthreads();
  }

  float* __restrict__ outb = out + (size_t)b * T * C;
  float rs[8] = {0.f}, rq[8] = {0.f};
#pragma unroll
  for (int j = 0; j < 8; j++) {
    int t = t0 + tx * 8 + j;
    if (t < T) {
      int o = ty * 8;
      float4 v0 = make_float4(acc[0][j], acc[1][j], acc[2][j], acc[3][j]);
      float4 v1 = make_float4(acc[4][j], acc[5][j], acc[6][j], acc[7][j]);
      *(float4*)(outb + (size_t)t * C + o) = v0;
      *(float4*)(outb + (size_t)t * C + o + 4) = v1;
#pragma unroll
      for (int i = 0; i < 8; i++) {
        rs[i] += acc[i][j];
        rq[i] += acc[i][j] * acc[i][j];
      }
    }
  }
#pragma unroll
  for (int i = 0; i < 8; i++) {
    atomicAdd(&ssum[ty * 8 + i], rs[i]);
    atomicAdd(&ssq[ty * 8 + i], rq[i]);
  }
  __syncthreads();
  int p = b * 4 + tile;
  if (tid < 128) {
    ps[tid * NPART + p] = ssum[tid];
    pq[tid * NPART + p] = ssq[tid];
  }
}

// ---------------------------------------------------------------------------
// Reduce partials -> mean, rstd per channel. grid (128[,2])
// ---------------------------------------------------------------------------
__global__ __launch_bounds__(256) void reduce_stats(
    const float* __restrict__ ps, const float* __restrict__ pq,
    float* __restrict__ om, float* __restrict__ orr, int npart) {
  int c = blockIdx.x;
  float s = 0.f, q = 0.f;
  for (int p = threadIdx.x; p < npart; p += 256) {
    s += ps[c * NPART + p];
    q += pq[c * NPART + p];
  }
  s = wave_sum(s);
  q = wave_sum(q);
  __shared__ float ls[8];
  int wv = threadIdx.x >> 6, ln = threadIdx.x & 63;
  if (ln == 0) { ls[wv] = s; ls[4 + wv] = q; }
  __syncthreads();
  if (threadIdx.x == 0) {
    float S = ls[0] + ls[1] + ls[2] + ls[3];
    float Q = ls[4] + ls[5] + ls[6] + ls[7];
    const float invn = 1.f / 64000.f;
    float m = S * invn;
    float v = Q * invn - m * m;
    om[c] = m;
    orr[c] = rsqrtf(v + 1e-5f);
  }
}

__global__ __launch_bounds__(256) void reduce_stats2(
    const float* __restrict__ ps2, const float* __restrict__ pq2,
    float* __restrict__ om2, float* __restrict__ or2,
    const float* __restrict__ ps3, const float* __restrict__ pq3,
    float* __restrict__ om3, float* __restrict__ or3) {
  const float* ps = blockIdx.y ? ps3 : ps2;
  const float* pq = blockIdx.y ? pq3 : pq2;
  float* om = blockIdx.y ? om3 : om2;
  float* orr = blockIdx.y ? or3 : or2;
  int c = blockIdx.x;
  float s = 0.f, q = 0.f;
  for (int p = threadIdx.x; p < NPART; p += 256) {
    s += ps[c * NPART + p];
    q += pq[c * NPART + p];
  }
  s = wave_sum(s);
  q = wave_sum(q);
  __shared__ float ls[8];
  int wv = threadIdx.x >> 6, ln = threadIdx.x & 63;
  if (ln == 0) { ls[wv] = s; ls[4 + wv] = q; }
  __syncthreads();
  if (threadIdx.x == 0) {
    float S = ls[0] + ls[1] + ls[2] + ls[3];
    float Q = ls[4] + ls[5] + ls[6] + ls[7];
    const float invn = 1.f / 64000.f;
    float m = S * invn;
    float v = Q * invn - m * m;
    om[c] = m;
    orr[c] = rsqrtf(v + 1e-5f);
  }
}

// ---------------------------------------------------------------------------
// In-place z = relu((z - m[c]) * r[c]), [b][t][c] layout. Used once (conv0).
// ---------------------------------------------------------------------------
__global__ __launch_bounds__(256) void apply_bn_relu(
    float* __restrict__ x, const float* __restrict__ m,
    const float* __restrict__ r) {
  __shared__ float sm[C], sr[C];
  if (threadIdx.x < 128) {
    sm[threadIdx.x] = m[threadIdx.x];
    sr[threadIdx.x] = r[threadIdx.x];
  }
  __syncthreads();
  const size_t total4 = NBCT / 4;
  size_t stride = (size_t)gridDim.x * 256;
  for (size_t i4 = (size_t)blockIdx.x * 256 + threadIdx.x; i4 < total4;
       i4 += stride) {
    int c = (int)((i4 & 31) * 4);
    float4 v = ((float4*)x)[i4];
    v.x = fmaxf((v.x - sm[c]) * sr[c], 0.f);
    v.y = fmaxf((v.y - sm[c + 1]) * sr[c + 1], 0.f);
    v.z = fmaxf((v.z - sm[c + 2]) * sr[c + 2], 0.f);
    v.w = fmaxf((v.w - sm[c + 3]) * sr[c + 3], 0.f);
    ((float4*)x)[i4] = v;
  }
}

// ---------------------------------------------------------------------------
// combine: k = relu(bn2(t2) + relu(bn3(t3))); RK4 update. [b][t][c] layout.
// ---------------------------------------------------------------------------
__global__ __launch_bounds__(256) void combine_kernel(
    const float* __restrict__ t2, const float* __restrict__ t3,
    const float* __restrict__ m2, const float* __restrict__ r2,
    const float* __restrict__ m3, const float* __restrict__ r3,
    const float* __restrict__ z, float* __restrict__ acc,
    float* __restrict__ zout, float wacc, float anext, int init, int fin) {
  __shared__ float sm2[C], sr2[C], sm3[C], sr3[C];
  if (threadIdx.x < 128) {
    sm2[threadIdx.x] = m2[threadIdx.x];
    sr2[threadIdx.x] = r2[threadIdx.x];
    sm3[threadIdx.x] = m3[threadIdx.x];
    sr3[threadIdx.x] = r3[threadIdx.x];
  }
  __syncthreads();
  const size_t total4 = NBCT / 4;
  size_t stride = (size_t)gridDim.x * 256;
  for (size_t i4 = (size_t)blockIdx.x * 256 + threadIdx.x; i4 < total4;
       i4 += stride) {
    int c = (int)((i4 & 31) * 4);
    size_t off = i4 * 4;
    float4 v2 = *(const float4*)(t2 + off);
    float4 v3 = *(const float4*)(t3 + off);
    float4 vz = *(const float4*)(z + off);
    float4 k;
    k.x = fmaxf((v2.x - sm2[c]) * sr2[c] + fmaxf((v3.x - sm3[c]) * sr3[c], 0.f), 0.f);
    k.y = fmaxf((v2.y - sm2[c + 1]) * sr2[c + 1] + fmaxf((v3.y - sm3[c + 1]) * sr3[c + 1], 0.f), 0.f);
    k.z = fmaxf((v2.z - sm2[c + 2]) * sr2[c + 2] + fmaxf((v3.z - sm3[c + 2]) * sr3[c + 2], 0.f), 0.f);
    k.w = fmaxf((v2.w - sm2[c + 3]) * sr2[c + 3] + fmaxf((v3.w - sm3[c + 3]) * sr3[c + 3], 0.f), 0.f);
    float4 va;
    if (init) {
      va.x = wacc * k.x; va.y = wacc * k.y; va.z = wacc * k.z; va.w = wacc * k.w;
    } else {
      va = *(const float4*)(acc + off);
      va.x += wacc * k.x; va.y += wacc * k.y; va.z += wacc * k.z; va.w += wacc * k.w;
    }
    *(float4*)(acc + off) = va;
    float4 vo;
    if (fin) {
      vo.x = vz.x + anext * va.x; vo.y = vz.y + anext * va.y;
      vo.z = vz.z + anext * va.z; vo.w = vz.w + anext * va.w;
    } else {
      vo.x = vz.x + anext * k.x; vo.y = vz.y + anext * k.y;
      vo.z = vz.z + anext * k.z; vo.w = vz.w + anext * k.w;
    }
    *(float4*)(zout + off) = vo;
  }
}

// ---------------------------------------------------------------------------
// head: feat[b][c] = mean_t z[b][t][c]; out[b][l] = feat . ow[l] + ob[l]
// ---------------------------------------------------------------------------
__global__ __launch_bounds__(256) void head_kernel(
    const float* __restrict__ z, const float* __restrict__ ow,
    const float* __restrict__ ob, float* __restrict__ out) {
  const int b = blockIdx.x;
  const int c = threadIdx.x & 127;
  const int half = threadIdx.x >> 7;
  const float* zb = z + (size_t)b * T * C;
  float s = 0.f;
  for (int t = half; t < T; t += 2) s += zb[(size_t)t * C + c];
  __shared__ float sf[2][C];
  sf[half][c] = s;
  __syncthreads();
  __shared__ float feat[C];
  if (threadIdx.x < 128) feat[threadIdx.x] =
      (sf[0][threadIdx.x] + sf[1][threadIdx.x]) * (1.f / 500.f);
  __syncthreads();
  if (threadIdx.x < NL) {
    int l = threadIdx.x;
    float o = ob[l];
    for (int j = 0; j < C; j++) o = fmaf(feat[j], ow[l * C + j], o);
    out[b * NL + l] = o;
  }
}

// ---------------------------------------------------------------------------
extern "C" void kernel_launch(void* const* d_in, const int* in_sizes, int n_in,
                              void* d_out, int out_size, void* d_ws,
                              size_t ws_size, hipStream_t stream) {
  const float* x  = (const float*)d_in[0];
  const float* w0 = (const float*)d_in[1];
  const float* w1 = (const float*)d_in[2];
  const float* w2 = (const float*)d_in[3];
  const float* w3 = (const float*)d_in[4];
  const float* ow = (const float*)d_in[5];
  const float* ob = (const float*)d_in[6];
  float* out = (float*)d_out;

  static float *z, *acc, *zin, *t1, *t2, *t3;
  static float *ps1, *pq1, *ps2, *pq2, *ps3, *pq3;
  static float *m1, *r1, *m2, *r2, *m3, *r3;
  static unsigned short *w1h, *w1l, *w2h, *w2l, *w3h, *w3l;
  static bool inited = false;
  if (!inited) {
    void* p;
#define GET(sym, var) hipGetSymbolAddress(&p, HIP_SYMBOL(sym)); var = (decltype(var))p;
    GET(g_z, z) GET(g_acc, acc) GET(g_zin, zin)
    GET(g_t1, t1) GET(g_t2, t2) GET(g_t3, t3)
    GET(g_ps1, ps1) GET(g_pq1, pq1) GET(g_ps2, ps2) GET(g_pq2, pq2)
    GET(g_ps3, ps3) GET(g_pq3, pq3)
    GET(g_m1, m1) GET(g_r1, r1) GET(g_m2, m2) GET(g_r2, r2)
    GET(g_m3, m3) GET(g_r3, r3)
    GET(g_w1h, w1h) GET(g_w1l, w1l) GET(g_w2h, w2h) GET(g_w2l, w2l)
    GET(g_w3h, w3h) GET(g_w3l, w3l)
#undef GET
    inited = true;
  }

  // Weight prep (cheap, every launch)
  prep_weights<9><<<(C * C * 9 + 255) / 256, 256, 0, stream>>>(w1, w1h, w1l);
  prep_weights<9><<<(C * C * 9 + 255) / 256, 256, 0, stream>>>(w2, w2h, w2l);
  prep_weights<1><<<(C * C * 1 + 255) / 256, 256, 0, stream>>>(w3, w3h, w3l);

  const dim3 conv0Grid(4, B);
  const dim3 convGrid(8, B);  // 8 t-tiles x 128 b
  const int ewGrid = 1024;
  const float dt = 0.25f;

  // conv0 -> bn -> relu (into z)
  conv0_kernel<<<conv0Grid, 256, 0, stream>>>(x, w0, z, ps1, pq1);
  reduce_stats<<<C, 256, 0, stream>>>(ps1, pq1, m1, r1, 512);
  apply_bn_relu<<<ewGrid, 256, 0, stream>>>(z, m1, r1);

  const float waccs[4] = {1.f, 2.f, 2.f, 1.f};
  const float anexts[4] = {0.5f * dt, 0.5f * dt, dt, dt / 6.f};

  for (int step = 0; step < 4; step++) {
    for (int s = 0; s < 4; s++) {
      const float* zin_s = (s == 0) ? z : zin;
      conv_mfma<9, 4, false><<<convGrid, 256, 0, stream>>>(
          zin_s, w1h, w1l, nullptr, nullptr, t1, ps1, pq1);
      reduce_stats<<<C, 256, 0, stream>>>(ps1, pq1, m1, r1, NPART);
      conv_mfma<9, 4, true><<<convGrid, 256, 0, stream>>>(
          t1, w2h, w2l, m1, r1, t2, ps2, pq2);
      conv_mfma<1, 0, false><<<convGrid, 256, 0, stream>>>(
          zin_s, w3h, w3l, nullptr, nullptr, t3, ps3, pq3);
      reduce_stats2<<<dim3(C, 2), 256, 0, stream>>>(
          ps2, pq2, m2, r2, ps3, pq3, m3, r3);
      combine_kernel<<<ewGrid, 256, 0, stream>>>(
          t2, t3, m2, r2, m3, r3, z, acc, (s == 3) ? z : zin,
          waccs[s], anexts[s], (s == 0) ? 1 : 0, (s == 3) ? 1 : 0);
    }
  }

  head_kernel<<<B, 256, 0, stream>>>(z, ow, ob, out);
}